// Round 1
// 539.436 us; speedup vs baseline: 1.1042x; 1.1042x over previous
//
#include <hip/hip_runtime.h>
#include <hip/hip_bf16.h>
#include <stdint.h>

typedef unsigned short ushort_t;
typedef __bf16 bf16x8 __attribute__((ext_vector_type(8)));
typedef float f32x4 __attribute__((ext_vector_type(4)));
typedef ushort_t ushort8v __attribute__((ext_vector_type(8)));

// ---------- helpers ----------

__device__ __forceinline__ ushort_t f2bf(float f) {
  // round-to-nearest-even bf16 (inputs finite normals)
  unsigned int u = __float_as_uint(f);
  u += 0x7FFFu + ((u >> 16) & 1u);
  return (ushort_t)(u >> 16);
}

typedef __attribute__((address_space(1))) void gvoid_t;
typedef __attribute__((address_space(3))) void lvoid_t;

__device__ __forceinline__ void async_cp16(const ushort_t* g, ushort_t* l) {
  // 16B/lane direct global->LDS DMA. LDS dest is wave-uniform base + lane*16.
  __builtin_amdgcn_global_load_lds((gvoid_t*)g, (lvoid_t*)l, 16, 0, 0);
}

// ---------- prep: x fp32 -> bf16 (8 elems/thread: 32B load, 16B store) ----------

__global__ __launch_bounds__(256) void cvt_x_kernel(const float4* __restrict__ x,
                                                    ushort8v* __restrict__ xb, int n8) {
  int i = blockIdx.x * 256 + threadIdx.x;
  if (i >= n8) return;
  float4 a = x[2 * i], b = x[2 * i + 1];
  ushort8v o;
  o[0] = f2bf(a.x); o[1] = f2bf(a.y); o[2] = f2bf(a.z); o[3] = f2bf(a.w);
  o[4] = f2bf(b.x); o[5] = f2bf(b.y); o[6] = f2bf(b.z); o[7] = f2bf(b.w);
  xb[i] = o;
}

// ---------- prep: weight quantize->dequant -> bf16 (exact in bf16) ----------

__device__ __forceinline__ float dq1(float w, float rs, float s, float z) {
  float q = rintf(w * rs + z);             // RNE, matches jnp.round
  q = fminf(fmaxf(q, 0.0f), 15.0f);
  return (q - z) * s;                      // int in [-15,15] * 2^e : exact in bf16
}

__global__ __launch_bounds__(256) void dequant_w_kernel(const float* __restrict__ w,
                                                        const float* __restrict__ sc,
                                                        const float* __restrict__ zp,
                                                        ushort8v* __restrict__ wq, int n8) {
  int i = blockIdx.x * 256 + threadIdx.x;
  if (i >= n8) return;
  int base = i * 8;
  int gi = base >> 5;                      // 8-elem span stays within one 32-group
  float s = sc[gi], z = zp[gi];
  float rs = 1.0f / s;                     // s = 2^e -> exact reciprocal
  const float4* w4 = (const float4*)(w + base);
  float4 a = w4[0], b = w4[1];
  ushort8v o;
  o[0] = f2bf(dq1(a.x, rs, s, z)); o[1] = f2bf(dq1(a.y, rs, s, z));
  o[2] = f2bf(dq1(a.z, rs, s, z)); o[3] = f2bf(dq1(a.w, rs, s, z));
  o[4] = f2bf(dq1(b.x, rs, s, z)); o[5] = f2bf(dq1(b.y, rs, s, z));
  o[6] = f2bf(dq1(b.z, rs, s, z)); o[7] = f2bf(dq1(b.w, rs, s, z));
  wq[i] = o;
}

// ---------- GEMM: C[M,N] = Xbf[M,K] @ Wbf[N,K]^T + bias ----------
// 256x256 tile, BK=64, 8 waves (2M x 4N), per-wave 128x64 via 8x4 of 16x16x32 MFMA.
// 8-phase schedule (T3+T4): per K-tile 4 phases, each {ds_read frags | issue
// global_load_lds for tile t+1 | raw s_barrier | lgkmcnt(0) | setprio(1) 16 MFMA
// setprio(0) | counted vmcnt | s_barrier}. vmcnt never drains to 0 in main loop:
//   vmcnt(6) end of P2 (drains prev tile's A1,A3 before P3 reads mh=1 rows)
//   vmcnt(2) end of P4 (drains next tile's B0-3,A0,A2 before its P1 reads)
// Staging for tile t+1 targets the buffer freed when tile t-1 finished -> no
// LDS WAR hazard. LDS layout: [row][8 chunks of 8 bf16], physical chunk =
// logical ^ (row&7), applied at the *global source address* (global_load_lds
// writes linearly) and at the ds_read address -> 0 bank conflicts (verified on
// the 128^2 predecessor).

#define BM 256
#define BN 256
#define BK 64

__device__ __forceinline__ f32x4 mfma16(bf16x8 a, bf16x8 b, f32x4 c) {
  return __builtin_amdgcn_mfma_f32_16x16x32_bf16(a, b, c, 0, 0, 0);
}

template <int MH, int NHB>
__device__ __forceinline__ void mfma_quad(f32x4 acc[2][4][4], const bf16x8 Afr[4][2],
                                          const bf16x8 Bfr[4][2]) {
#pragma unroll
  for (int k = 0; k < 2; ++k)
#pragma unroll
    for (int mt = 0; mt < 4; ++mt)
#pragma unroll
      for (int nt = 0; nt < 2; ++nt)
        acc[MH][mt][NHB * 2 + nt] =
            mfma16(Afr[mt][k], Bfr[NHB * 2 + nt][k], acc[MH][mt][NHB * 2 + nt]);
}

__global__ __launch_bounds__(512, 2) void gemm_bt_bias_kernel(
    const ushort_t* __restrict__ A,   // [M,K] bf16 bits
    const ushort_t* __restrict__ B,   // [N,K] bf16 bits
    const float* __restrict__ bias,   // [N]
    float* __restrict__ C,            // [M,N] fp32
    int M, int N, int K) {
  __shared__ ushort_t sA[2][BM * BK];   // 32 KB per buffer
  __shared__ ushort_t sB[2][BN * BK];   // total 128 KB

  const int tid  = threadIdx.x;
  const int wave = tid >> 6;
  const int lane = tid & 63;
  const int l15 = lane & 15, l4 = lane >> 4;

  // T1: bijective XCD swizzle (grid=512, 512%8==0)
  int wg = blockIdx.x;
  const int nwg = gridDim.x;
  if ((nwg & 7) == 0) wg = (wg & 7) * (nwg >> 3) + (wg >> 3);
  const int nbn = N / BN;
  const int m0 = (wg / nbn) * BM, n0 = (wg % nbn) * BN;
  const int wm = (wave >> 2) * 128, wn = (wave & 3) * 64;

  // staging: issue s covers rows [s*64, s*64+64); chunk = s*512 + tid,
  // row = chunk>>3, physical col-chunk = tid&7 holds logical (tid&7)^(row&7).
  const int srow = tid >> 3;
  const int scol = ((tid & 7) ^ (srow & 7)) * 8;   // pre-swizzled source col (elems)
  const int ldst = wave * 64 * 8;                  // wave-uniform LDS chunk base

  // fragment read: row = base16 + l15 -> row&7 = l15&7
  const int xa  = l15 & 7;
  const int pc0 = (l4 ^ xa) << 3;                  // kk=0 physical col
  const int pc1 = ((4 + l4) ^ xa) << 3;            // kk=32 physical col
  const int aoff = (wm + l15) * BK;
  const int boff = (wn + l15) * BK;

  f32x4 acc[2][4][4] = {};
  bf16x8 Afr[4][2], Bfr[4][2];

#define STAGE_A(sb, s, kn) \
  async_cp16(A + (size_t)(m0 + (s) * 64 + srow) * K + (kn) + scol, &sA[sb][(s) * 4096 + ldst])
#define STAGE_B(sb, s, kn) \
  async_cp16(B + (size_t)(n0 + (s) * 64 + srow) * K + (kn) + scol, &sB[sb][(s) * 4096 + ldst])
#define LDA(rb, mh, mt, k) \
  (*(const bf16x8*)&sA[rb][aoff + ((mh) * 64 + (mt) * 16) * BK + ((k) ? pc1 : pc0)])
#define LDB(rb, nt, k) \
  (*(const bf16x8*)&sB[rb][boff + (nt) * 16 * BK + ((k) ? pc1 : pc0)])
#define BAR()   __builtin_amdgcn_s_barrier()
#define LGKM0() asm volatile("s_waitcnt lgkmcnt(0)" ::: "memory")
#define VM(n)   asm volatile("s_waitcnt vmcnt(" #n ")" ::: "memory")
#define PRIO(p) __builtin_amdgcn_s_setprio(p)

  // prologue: stage tile 0 -> buf 0, order B0,B1,A0,B2,B3,A2,A1,A3.
  // vmcnt(2): first 6 issues landed (needed by P1/P2); A1,A3 may stay in flight.
  STAGE_B(0, 0, 0); STAGE_B(0, 1, 0); STAGE_A(0, 0, 0);
  STAGE_B(0, 2, 0); STAGE_B(0, 3, 0); STAGE_A(0, 2, 0);
  STAGE_A(0, 1, 0); STAGE_A(0, 3, 0);
  VM(2);
  BAR();

  const int nK = K / BK;
#pragma unroll 2
  for (int t = 0; t < nK - 1; ++t) {
    const int rb = t & 1, sb = rb ^ 1;
    const int kn = (t + 1) * BK;
    // ---- P1: quadrant (mh0, nh0) ----
#pragma unroll
    for (int mt = 0; mt < 4; ++mt) { Afr[mt][0] = LDA(rb, 0, mt, 0); Afr[mt][1] = LDA(rb, 0, mt, 1); }
#pragma unroll
    for (int nt = 0; nt < 2; ++nt) { Bfr[nt][0] = LDB(rb, nt, 0); Bfr[nt][1] = LDB(rb, nt, 1); }
    STAGE_B(sb, 0, kn); STAGE_B(sb, 1, kn); STAGE_A(sb, 0, kn);
    BAR(); LGKM0();
    PRIO(1); mfma_quad<0, 0>(acc, Afr, Bfr); PRIO(0);
    BAR();
    // ---- P2: quadrant (mh0, nh1) ----
#pragma unroll
    for (int nt = 2; nt < 4; ++nt) { Bfr[nt][0] = LDB(rb, nt, 0); Bfr[nt][1] = LDB(rb, nt, 1); }
    STAGE_B(sb, 2, kn); STAGE_B(sb, 3, kn); STAGE_A(sb, 2, kn);
    BAR(); LGKM0();
    PRIO(1); mfma_quad<0, 1>(acc, Afr, Bfr); PRIO(0);
    VM(6);   // drains prev tile's A1,A3 (issued 2 phases ago) -> P3 reads safe
    BAR();
    // ---- P3: quadrant (mh1, nh0) ----
#pragma unroll
    for (int mt = 0; mt < 4; ++mt) { Afr[mt][0] = LDA(rb, 1, mt, 0); Afr[mt][1] = LDA(rb, 1, mt, 1); }
    STAGE_A(sb, 1, kn); STAGE_A(sb, 3, kn);
    BAR(); LGKM0();
    PRIO(1); mfma_quad<1, 0>(acc, Afr, Bfr); PRIO(0);
    BAR();
    // ---- P4: quadrant (mh1, nh1) ----
    PRIO(1); mfma_quad<1, 1>(acc, Afr, Bfr); PRIO(0);
    VM(2);   // drains next tile's B0-3,A0,A2 (issued >=2 phases ago)
    BAR();
  }

  // ---- last tile: no staging; drain A1,A3 before P3 ----
  {
    const int rb = (nK - 1) & 1;
#pragma unroll
    for (int mt = 0; mt < 4; ++mt) { Afr[mt][0] = LDA(rb, 0, mt, 0); Afr[mt][1] = LDA(rb, 0, mt, 1); }
#pragma unroll
    for (int nt = 0; nt < 2; ++nt) { Bfr[nt][0] = LDB(rb, nt, 0); Bfr[nt][1] = LDB(rb, nt, 1); }
    BAR(); LGKM0();
    PRIO(1); mfma_quad<0, 0>(acc, Afr, Bfr); PRIO(0);
    BAR();
#pragma unroll
    for (int nt = 2; nt < 4; ++nt) { Bfr[nt][0] = LDB(rb, nt, 0); Bfr[nt][1] = LDB(rb, nt, 1); }
    BAR(); LGKM0();
    PRIO(1); mfma_quad<0, 1>(acc, Afr, Bfr); PRIO(0);
    VM(0);
    BAR();
#pragma unroll
    for (int mt = 0; mt < 4; ++mt) { Afr[mt][0] = LDA(rb, 1, mt, 0); Afr[mt][1] = LDA(rb, 1, mt, 1); }
    BAR(); LGKM0();
    PRIO(1); mfma_quad<1, 0>(acc, Afr, Bfr); PRIO(0);
    BAR();
    PRIO(1); mfma_quad<1, 1>(acc, Afr, Bfr); PRIO(0);
  }

  // epilogue: C/D layout col = lane&15, row = (lane>>4)*4 + reg
  const int ccol = n0 + wn + l15;
  const int crow = m0 + wm + l4 * 4;
#pragma unroll
  for (int nt = 0; nt < 4; ++nt) {
    const float bv = bias[ccol + nt * 16];
#pragma unroll
    for (int mh = 0; mh < 2; ++mh)
#pragma unroll
      for (int mt = 0; mt < 4; ++mt)
#pragma unroll
        for (int r = 0; r < 4; ++r)
          C[(size_t)(crow + mh * 64 + mt * 16 + r) * N + ccol + nt * 16] =
              acc[mh][mt][nt][r] + bv;
  }
}

// ---------- launch ----------

extern "C" void kernel_launch(void* const* d_in, const int* in_sizes, int n_in,
                              void* d_out, int out_size, void* d_ws, size_t ws_size,
                              hipStream_t stream) {
  const float* x    = (const float*)d_in[0];  // [M,K] fp32
  const float* w    = (const float*)d_in[1];  // [N,K] fp32
  const float* bias = (const float*)d_in[2];  // [N]
  const float* sc   = (const float*)d_in[3];  // [N, K/32]
  const float* zp   = (const float*)d_in[4];  // [N, K/32]
  float* out = (float*)d_out;

  const int N = in_sizes[2];       // 4096
  const int K = in_sizes[1] / N;   // 4096
  const int M = in_sizes[0] / K;   // 8192

  ushort_t* xb = (ushort_t*)d_ws;                 // M*K bf16 = 64 MB
  ushort_t* wq = xb + (size_t)M * K;              // N*K bf16 = 32 MB

  int xn8 = (M * K) / 8;
  cvt_x_kernel<<<(xn8 + 255) / 256, 256, 0, stream>>>((const float4*)x, (ushort8v*)xb, xn8);

  int wn8 = (N * K) / 8;
  dequant_w_kernel<<<(wn8 + 255) / 256, 256, 0, stream>>>(w, sc, zp, (ushort8v*)wq, wn8);

  dim3 grid((M / BM) * (N / BN));   // 512 blocks, %8==0 for XCD swizzle
  gemm_bt_bias_kernel<<<grid, 512, 0, stream>>>(xb, wq, bias, out, M, N, K);
}